// Round 21
// baseline (202.034 us; speedup 1.0000x reference)
//
#include <hip/hip_runtime.h>
#include <hip/hip_bf16.h>

#define NN 100000
#define DEG 16
#define NF 128
#define HID 128
#define NC 16
#define NB 10000

#define AS1 __attribute__((address_space(1)))
#define AS3 __attribute__((address_space(3)))

typedef float f32x16 __attribute__((ext_vector_type(16)));
typedef short s16x8 __attribute__((ext_vector_type(8)));

__device__ __forceinline__ ushort f2bf(float f) {   // RNE (prep kernel only)
    unsigned u = __builtin_bit_cast(unsigned, f);
    return (ushort)((u + 0x7FFFu + ((u >> 16) & 1u)) >> 16);
}
__device__ __forceinline__ float bf2f(ushort h) {
    return __builtin_bit_cast(float, (unsigned)h << 16);
}
// HW packed fp32->bf16 RNE: dst = {lo: cvt(a), hi: cvt(b)}
__device__ __forceinline__ uint cvtpk(float a, float b) {
    uint r;
    asm("v_cvt_pk_bf16_f32 %0, %1, %2" : "=v"(r) : "v"(a), "v"(b));
    return r;
}
__device__ __forceinline__ s16x8 pack8(float4 a, float4 b) {
    uint4 u;
    u.x = cvtpk(a.x, a.y);
    u.y = cvtpk(a.z, a.w);
    u.z = cvtpk(b.x, b.y);
    u.w = cvtpk(b.z, b.w);
    return __builtin_bit_cast(s16x8, u);
}
// XOR swizzle within a 256B LDS row: 16 slots of 16B (T2, conflict-free b128)
__device__ __forceinline__ int swz16(int row, int bo) {
    return row * 256 + (bo ^ ((row & 15) << 4));
}
// XOR swizzle for the 512B fp32 A-rows in gemm1 (32 slots of 16B)
__device__ __forceinline__ uint swzA(uint row, uint bo) {
    return bo ^ ((row & 31u) << 4);
}
// pi: storage position p -> true feature index j (within 128)
__device__ __forceinline__ int pi_feat(int p) {
    const int n = p >> 5, h = (p >> 4) & 1, g = p & 15;
    return 32 * n + 4 * h + (g & 3) + 8 * (g >> 2);
}
// Dense tile layout (this round's change):
//   Qb: tile*16384 + chunk*2048 + nl*32  (chunk = 16 bf16 = 32B/node)
//   Pf: tile*8192  + chunk*1024 + nl*16  (chunk = 16 fp8  = 16B/node)
//   tile = node>>6, nl = node&63, chunk = pi-position/16 (= 2n+h = sl)

// ---------------------------------------------------------------------------
// Prep: W1 -> bf16 MFMA A-fragments WFh; W2 -> WF2 with pi-permuted k.
// WFh frag (c,kk): lane l holds Wb[c*32+(l&31)][kk*16+(l>>5)*8 .. +8]
//   Wb[j][k] = j<128 ? W1[j][k] : W1[j-128][128+k]
// WF2 frag (kk):   lane l, elem i holds W2b[(l&31)][pi(kk*16+(l>>5)*8+i)]
// ---------------------------------------------------------------------------
__global__ __launch_bounds__(256)
void wf_prep(const float* __restrict__ W1, const float* __restrict__ W2,
             ushort* __restrict__ WFh, ushort* __restrict__ WF2) {
    const int t = blockIdx.x * 256 + threadIdx.x;
    if (t >= 72 * 64) return;
    const int frag = t >> 6;
    const int lane = t & 63;
    const int k0 = (frag & 7) * 16 + (lane >> 5) * 8;

    if (frag < 64) {
        const int vcol = (frag >> 3) * 32 + (lane & 31);
        const float* src = (vcol < 128) ? W1 + (size_t)vcol * 256
                                        : W1 + (size_t)(vcol - 128) * 256 + 128;
        ushort hh[8];
        #pragma unroll
        for (int j = 0; j < 8; ++j) hh[j] = f2bf(src[k0 + j]);
        *(uint4*)(WFh + (size_t)t * 8) = *(const uint4*)hh;
    } else {
        const int vcol = lane & 31;
        const float* src = (vcol < 16) ? W2 + (size_t)vcol * 256
                                       : W2 + (size_t)(vcol - 16) * 256 + 128;
        ushort hh[8];
        #pragma unroll
        for (int j = 0; j < 8; ++j) hh[j] = f2bf(src[pi_feat(k0 + j)]);
        *(uint4*)(WF2 + (size_t)((frag - 64) * 64 + lane) * 8) = *(const uint4*)hh;
    }
}

// ---------------------------------------------------------------------------
// GEMM1 (2-phase pipeline + register-resident B + DENSE tile-layout stores):
// 512 blocks, grid-strided tiles of 64 nodes (blocks 0..26 take 4 tiles,
// rest 3; 485*3+27*4 = 1563). Double-buffered 64KB LDS.
// Epilogue stores to the dense tile layout: each frag's store = two 1KB dense
// runs (32 lanes x 32B) instead of 64 scattered 16B pieces.
// ---------------------------------------------------------------------------
__global__ __launch_bounds__(256, 2)
void gemm1(const float* __restrict__ X, const ushort* __restrict__ WFh,
           char* __restrict__ Qb8, unsigned char* __restrict__ Pf) {
    __shared__ char As[2][32768];   // 2 x 32KB: 64 rows x 128 fp32, XOR-swizzled
    const int t = threadIdx.x;
    const int lane = t & 63;
    const int w = t >> 6;          // 0..3
    const int wm = w & 1;          // node frag
    const int wn = w >> 1;         // feature half
    const int bid = blockIdx.x;
    const int nt = (bid < 27) ? 4 : 3;

    // ---- preload B fragments for this wave's column-half (reused all tiles)
    s16x8 Bf[32];
    #pragma unroll
    for (int kk = 0; kk < 8; ++kk) {
        #pragma unroll
        for (int n = 0; n < 4; ++n) {
            const int cf = wn * 4 + n;
            Bf[kk * 4 + n] = *(const s16x8*)(WFh + (size_t)((cf * 8 + kk) * 64 + lane) * 8);
        }
    }

    // ---- prologue: stage tile 0 (= tile index bid) -> As[0]
    {
        const int row0 = bid * 64;
        #pragma unroll
        for (int j = 0; j < 8; ++j) {
            const uint chunk = (uint)(j * 4 + w);
            const uint o = chunk * 1024u + (uint)lane * 16u;
            const uint rrow = o >> 9;
            const uint bo = o & 511u;
            int grow = row0 + (int)rrow;
            if (grow > NN - 1) grow = NN - 1;
            const char* src = (const char*)X + (size_t)grow * 512 + swzA(rrow, bo);
            __builtin_amdgcn_global_load_lds((const AS1 void*)src,
                                             (AS3 void*)(As[0] + chunk * 1024), 16, 0, 0);
        }
    }
    __syncthreads();

    const uint arow = (uint)(wm * 32 + (lane & 31));

    for (int r = 0; r < nt; ++r) {
        const int cur = r & 1;
        // ---- issue next tile's loads into the other buffer (async)
        if (r + 1 < nt) {
            const int row0n = (bid + (r + 1) * 512) * 64;
            #pragma unroll
            for (int j = 0; j < 8; ++j) {
                const uint chunk = (uint)(j * 4 + w);
                const uint o = chunk * 1024u + (uint)lane * 16u;
                const uint rrow = o >> 9;
                const uint bo = o & 511u;
                int grow = row0n + (int)rrow;
                if (grow > NN - 1) grow = NN - 1;
                const char* src = (const char*)X + (size_t)grow * 512 + swzA(rrow, bo);
                __builtin_amdgcn_global_load_lds((const AS1 void*)src,
                                                 (AS3 void*)(As[cur ^ 1] + chunk * 1024),
                                                 16, 0, 0);
            }
        }
        __builtin_amdgcn_sched_barrier(0);   // pin: issue prefetch before compute

        // ---- compute current tile (LDS + registers only)
        const int tileIdx = bid + r * 512;
        const int row0 = tileIdx * 64;
        const char* abase = As[cur] + arow * 512;

        f32x16 acc[4];
        #pragma unroll
        for (int n = 0; n < 4; ++n)
            acc[n] = (f32x16){0,0,0,0,0,0,0,0,0,0,0,0,0,0,0,0};

        #pragma unroll
        for (int kk = 0; kk < 8; ++kk) {
            const uint bo = (uint)(kk * 64 + (lane >> 5) * 32);
            const float4 fa = *(const float4*)(abase + swzA(arow, bo));
            const float4 fb = *(const float4*)(abase + swzA(arow, bo + 16));
            const s16x8 a = pack8(fa, fb);
            #pragma unroll
            for (int n = 0; n < 4; ++n) {
                // swapped: W as A (row=feature), X as B (col=node)
                acc[n] = __builtin_amdgcn_mfma_f32_32x32x16_bf16(Bf[kk * 4 + n], a, acc[n], 0, 0, 0);
            }
        }

        // ---- epilogue: DENSE tile-layout stores.
        // Per frag n: positions n*32+h*16+(0..15) = chunk c = 2n+h.
        const int nl = wm * 32 + (lane & 31);
        const int node = row0 + nl;
        const int h = lane >> 5;
        if (node < NN) {
            if (wn == 0) {
                char* qbase = Qb8 + (size_t)tileIdx * 16384 + (size_t)nl * 32;
                #pragma unroll
                for (int n = 0; n < 4; ++n) {
                    const int c = n * 2 + h;
                    uint4 u0, u1;
                    u0.x = cvtpk(acc[n][0], acc[n][1]);
                    u0.y = cvtpk(acc[n][2], acc[n][3]);
                    u0.z = cvtpk(acc[n][4], acc[n][5]);
                    u0.w = cvtpk(acc[n][6], acc[n][7]);
                    u1.x = cvtpk(acc[n][8], acc[n][9]);
                    u1.y = cvtpk(acc[n][10], acc[n][11]);
                    u1.z = cvtpk(acc[n][12], acc[n][13]);
                    u1.w = cvtpk(acc[n][14], acc[n][15]);
                    *(uint4*)(qbase + c * 2048) = u0;
                    *(uint4*)(qbase + c * 2048 + 16) = u1;
                }
            } else {
                unsigned char* pbase = Pf + (size_t)tileIdx * 8192 + (size_t)nl * 16;
                #pragma unroll
                for (int n = 0; n < 4; ++n) {
                    const int c = n * 2 + h;
                    uint uu[4];
                    #pragma unroll
                    for (int q = 0; q < 4; ++q) {
                        int v = __builtin_amdgcn_cvt_pk_fp8_f32(
                            acc[n][4 * q], acc[n][4 * q + 1], 0, false);
                        v = __builtin_amdgcn_cvt_pk_fp8_f32(
                            acc[n][4 * q + 2], acc[n][4 * q + 3], v, true);
                        uu[q] = (uint)v;
                    }
                    *(uint4*)(pbase + c * 1024) = *(const uint4*)uu;
                }
            }
        }
        __syncthreads();   // next tile's loads landed; everyone done with As[cur]
    }
}

// ---------------------------------------------------------------------------
// Fused aggregate + GEMM2 (dense tile-layout reads; values unchanged).
// Block = 128 nodes, 32KB LDS. (256,3): 3 blocks/CU.
// Phase A: h1[n] = relu(Q[n] + mean_d P[nbr(n,d)]) -> swizzled LDS (bf16).
// Phase B: ST = h1pi @ WF2pi (MFMA from LDS) -> STb (bf16, true order).
// ---------------------------------------------------------------------------
__global__ __launch_bounds__(256, 3)
void agg_gemm2(const int* __restrict__ nidx, const unsigned char* __restrict__ Pf,
               const char* __restrict__ Qb8, const ushort* __restrict__ WF2,
               ushort* __restrict__ STb) {
    __shared__ char hs[128 * 256];  // 32KB: 128 rows x 128 bf16, swizzled
    const int t = threadIdx.x;
    const int node0 = blockIdx.x * 128;
    const int sl = t & 7;    // chunk index (16 pi-positions)
    const int ng = t >> 3;   // node slot 0..31

    const float inv = 1.0f / 16.0f;
    #pragma unroll 1
    for (int it = 0; it < 4; ++it) {
        const int r = ng + it * 32;          // local row 0..127
        int node = node0 + r;
        if (node > NN - 1) node = NN - 1;
        const int2 myn = *(const int2*)(nidx + (size_t)node * DEG + sl * 2);
        // Q read: chunk sl of node's row in the dense tile layout
        const ushort* qp = (const ushort*)(Qb8 + (size_t)(node >> 6) * 16384
                                           + (size_t)sl * 2048 + (size_t)(node & 63) * 32);
        const s16x8 q0 = *(const s16x8*)qp;
        const s16x8 q1 = *(const s16x8*)(qp + 8);

        uint4 vv[16];
        #pragma unroll
        for (int d = 0; d < 16; ++d) {
            const uint id = (uint)__shfl((d & 1) ? myn.y : myn.x, d >> 1, 8);
            vv[d] = *(const uint4*)(Pf + (size_t)(id >> 6) * 8192
                                    + (size_t)sl * 1024 + (size_t)(id & 63) * 16);
        }
        __builtin_amdgcn_sched_barrier(0);   // all 16 gathers in flight first

        float s[16];
        #pragma unroll
        for (int j = 0; j < 16; ++j) s[j] = 0.f;
        #pragma unroll
        for (int d = 0; d < 16; ++d) {
            const uint wd[4] = {vv[d].x, vv[d].y, vv[d].z, vv[d].w};
            #pragma unroll
            for (int q = 0; q < 4; ++q) {
                const auto plo = __builtin_amdgcn_cvt_pk_f32_fp8(wd[q], false);
                const auto phi = __builtin_amdgcn_cvt_pk_f32_fp8(wd[q], true);
                s[q * 4 + 0] += plo[0]; s[q * 4 + 1] += plo[1];
                s[q * 4 + 2] += phi[0]; s[q * 4 + 3] += phi[1];
            }
        }

        float h[16];
        #pragma unroll
        for (int j = 0; j < 8; ++j) {
            h[j]     = fmaxf(fmaf(s[j],     inv, bf2f((ushort)q0[j])), 0.f);
            h[j + 8] = fmaxf(fmaf(s[j + 8], inv, bf2f((ushort)q1[j])), 0.f);
        }
        uint4 u0, u1;
        u0.x = cvtpk(h[0], h[1]);   u0.y = cvtpk(h[2], h[3]);
        u0.z = cvtpk(h[4], h[5]);   u0.w = cvtpk(h[6], h[7]);
        u1.x = cvtpk(h[8], h[9]);   u1.y = cvtpk(h[10], h[11]);
        u1.z = cvtpk(h[12], h[13]); u1.w = cvtpk(h[14], h[15]);
        *(uint4*)(hs + swz16(r, sl * 32)) = u0;
        *(uint4*)(hs + swz16(r, sl * 32 + 16)) = u1;
    }
    __syncthreads();

    // Phase B: 4 waves; wave w -> local rows w*32 .. w*32+31 (1 frag)
    const int lane = t & 63;
    const int w = t >> 6;
    const int rl = w * 32;

    f32x16 acc = {0,0,0,0,0,0,0,0,0,0,0,0,0,0,0,0};
    #pragma unroll
    for (int kk = 0; kk < 8; ++kk) {
        const int kb = kk * 32 + (lane >> 5) * 16;
        const s16x8 a = *(const s16x8*)(hs + swz16(rl + (lane & 31), kb));
        const s16x8 b = *(const s16x8*)(WF2 + (size_t)(kk * 64 + lane) * 8);
        acc = __builtin_amdgcn_mfma_f32_32x32x16_bf16(a, b, acc, 0, 0, 0);
    }

    const int col = lane & 31;
    const int crow4 = 4 * (lane >> 5);
    #pragma unroll
    for (int g = 0; g < 16; g += 2) {
        const uint pk = cvtpk(acc[g], acc[g + 1]);
        const int row = node0 + rl + (g & 3) + 8 * (g >> 2) + crow4;
        if (row < NN)     STb[(size_t)row * 32 + col] = (ushort)pk;
        if (row + 1 < NN) STb[(size_t)(row + 1) * 32 + col] = (ushort)(pk >> 16);
    }
}

// ---------------------------------------------------------------------------
// Final: out[b][j] = S[node_b][j] + (1/16)*sum_d T[nbr(node_b,d)][j]
// ---------------------------------------------------------------------------
__global__ __launch_bounds__(256)
void final_out(const int* __restrict__ nodes, const int* __restrict__ nidx,
               const ushort* __restrict__ STb, float* __restrict__ out) {
    const int g = blockIdx.x * 256 + threadIdx.x;
    if (g >= NB * NC / 2) return;
    const int b = g >> 3;
    const int jp = g & 7;
    const int node = nodes[b];
    const uint sv = *(const uint*)(STb + (size_t)node * 32 + jp * 2);
    const int* nb = nidx + (size_t)node * DEG;
    float a0 = 0.f, a1 = 0.f;
    #pragma unroll
    for (int d = 0; d < DEG; ++d) {
        const uint v = *(const uint*)(STb + (size_t)nb[d] * 32 + 16 + jp * 2);
        a0 += bf2f((ushort)v);
        a1 += bf2f((ushort)(v >> 16));
    }
    float2 o;
    o.x = fmaf(a0, 1.0f / 16.0f, bf2f((ushort)sv));
    o.y = fmaf(a1, 1.0f / 16.0f, bf2f((ushort)(sv >> 16)));
    *(float2*)(out + (size_t)b * 16 + jp * 2) = o;
}

extern "C" void kernel_launch(void* const* d_in, const int* in_sizes, int n_in,
                              void* d_out, int out_size, void* d_ws, size_t ws_size,
                              hipStream_t stream) {
    const int* nodes = (const int*)d_in[0];
    const int* nidx  = (const int*)d_in[1];
    const float* X   = (const float*)d_in[2];
    const float* W1  = (const float*)d_in[3];
    const float* W2  = (const float*)d_in[4];
    float* out = (float*)d_out;

    // ws: Qb 1563*16KB = 25.6MB | Pf 1563*8KB = 12.8MB | STb 6.4MB | WFh | WF2
    char* Qb8 = (char*)d_ws;
    unsigned char* Pf = (unsigned char*)(Qb8 + (size_t)1563 * 16384);
    ushort* STb = (ushort*)(Pf + (size_t)1563 * 8192);
    ushort* WFh = STb + (size_t)NN * 32;
    ushort* WF2 = WFh + 64 * 64 * 8;

    wf_prep<<<18, 256, 0, stream>>>(W1, W2, WFh, WF2);
    gemm1<<<512, 256, 0, stream>>>(X, WFh, Qb8, Pf);   // grid-strided: 512 blocks, 3-4 tiles
    agg_gemm2<<<782, 256, 0, stream>>>(nidx, Pf, Qb8, WF2, STb);
    final_out<<<313, 256, 0, stream>>>(nodes, nidx, STb, out);
}

// Round 22
// 64.205 us; speedup vs baseline: 3.1467x; 3.1467x over previous
//
#include <hip/hip_runtime.h>
#include <hip/hip_bf16.h>

#define NN 100000
#define DEG 16
#define NF 128
#define HID 128
#define NC 16
#define NB 10000

#define AS1 __attribute__((address_space(1)))
#define AS3 __attribute__((address_space(3)))

typedef float f32x16 __attribute__((ext_vector_type(16)));
typedef short s16x8 __attribute__((ext_vector_type(8)));

__device__ __forceinline__ ushort f2bf(float f) {   // RNE (prep kernel only)
    unsigned u = __builtin_bit_cast(unsigned, f);
    return (ushort)((u + 0x7FFFu + ((u >> 16) & 1u)) >> 16);
}
__device__ __forceinline__ float bf2f(ushort h) {
    return __builtin_bit_cast(float, (unsigned)h << 16);
}
// HW packed fp32->bf16 RNE: dst = {lo: cvt(a), hi: cvt(b)}
__device__ __forceinline__ uint cvtpk(float a, float b) {
    uint r;
    asm("v_cvt_pk_bf16_f32 %0, %1, %2" : "=v"(r) : "v"(a), "v"(b));
    return r;
}
__device__ __forceinline__ s16x8 pack8(float4 a, float4 b) {
    uint4 u;
    u.x = cvtpk(a.x, a.y);
    u.y = cvtpk(a.z, a.w);
    u.z = cvtpk(b.x, b.y);
    u.w = cvtpk(b.z, b.w);
    return __builtin_bit_cast(s16x8, u);
}
// XOR swizzle within a 256B LDS row: 16 slots of 16B (T2, conflict-free b128)
__device__ __forceinline__ int swz16(int row, int bo) {
    return row * 256 + (bo ^ ((row & 15) << 4));
}
// XOR swizzle for the 512B fp32 A-rows in gemm1 (32 slots of 16B)
__device__ __forceinline__ uint swzA(uint row, uint bo) {
    return bo ^ ((row & 31u) << 4);
}
// pi: storage position p -> true feature index j (within 128)
__device__ __forceinline__ int pi_feat(int p) {
    const int n = p >> 5, h = (p >> 4) & 1, g = p & 15;
    return 32 * n + 4 * h + (g & 3) + 8 * (g >> 2);
}

// ---------------------------------------------------------------------------
// Prep: W1 -> bf16 MFMA A-fragments WFh; W2 -> WF2 with pi-permuted k.
// WFh frag (c,kk): lane l holds Wb[c*32+(l&31)][kk*16+(l>>5)*8 .. +8]
//   Wb[j][k] = j<128 ? W1[j][k] : W1[j-128][128+k]
// WF2 frag (kk):   lane l, elem i holds W2b[(l&31)][pi(kk*16+(l>>5)*8+i)]
// ---------------------------------------------------------------------------
__global__ __launch_bounds__(256)
void wf_prep(const float* __restrict__ W1, const float* __restrict__ W2,
             ushort* __restrict__ WFh, ushort* __restrict__ WF2) {
    const int t = blockIdx.x * 256 + threadIdx.x;
    if (t >= 72 * 64) return;
    const int frag = t >> 6;
    const int lane = t & 63;
    const int k0 = (frag & 7) * 16 + (lane >> 5) * 8;

    if (frag < 64) {
        const int vcol = (frag >> 3) * 32 + (lane & 31);
        const float* src = (vcol < 128) ? W1 + (size_t)vcol * 256
                                        : W1 + (size_t)(vcol - 128) * 256 + 128;
        ushort hh[8];
        #pragma unroll
        for (int j = 0; j < 8; ++j) hh[j] = f2bf(src[k0 + j]);
        *(uint4*)(WFh + (size_t)t * 8) = *(const uint4*)hh;
    } else {
        const int vcol = lane & 31;
        const float* src = (vcol < 16) ? W2 + (size_t)vcol * 256
                                       : W2 + (size_t)(vcol - 16) * 256 + 128;
        ushort hh[8];
        #pragma unroll
        for (int j = 0; j < 8; ++j) hh[j] = f2bf(src[pi_feat(k0 + j)]);
        *(uint4*)(WF2 + (size_t)((frag - 64) * 64 + lane) * 8) = *(const uint4*)hh;
    }
}

// ---------------------------------------------------------------------------
// GEMM1 (2-phase pipeline + register-resident B): 512 blocks, grid-strided
// tiles of 64 nodes (blocks 0..26 take 4 tiles, rest 3; 485*3+27*4 = 1563).
// Double-buffered 64KB LDS. B-fragments (32 x s16x8 = 128 VGPR) loaded once
// per block from WFh (flight hides under prologue stage + sync), reused
// across all tiles -> per-tile compute touches no global memory.
// NOTE: Qb/Pf stay ROW-CONTIGUOUS per node — r21 proved the gather's read
// locality depends on it (chunked layout = 3x FETCH, 3.1x slower).
// ---------------------------------------------------------------------------
__global__ __launch_bounds__(256, 2)
void gemm1(const float* __restrict__ X, const ushort* __restrict__ WFh,
           ushort* __restrict__ Qb, unsigned char* __restrict__ Pf) {
    __shared__ char As[2][32768];   // 2 x 32KB: 64 rows x 128 fp32, XOR-swizzled
    const int t = threadIdx.x;
    const int lane = t & 63;
    const int w = t >> 6;          // 0..3
    const int wm = w & 1;          // node frag
    const int wn = w >> 1;         // feature half
    const int bid = blockIdx.x;
    const int nt = (bid < 27) ? 4 : 3;

    // ---- preload B fragments for this wave's column-half (reused all tiles)
    s16x8 Bf[32];
    #pragma unroll
    for (int kk = 0; kk < 8; ++kk) {
        #pragma unroll
        for (int n = 0; n < 4; ++n) {
            const int cf = wn * 4 + n;
            Bf[kk * 4 + n] = *(const s16x8*)(WFh + (size_t)((cf * 8 + kk) * 64 + lane) * 8);
        }
    }

    // ---- prologue: stage tile 0 (= tile index bid) -> As[0]
    {
        const int row0 = bid * 64;
        #pragma unroll
        for (int j = 0; j < 8; ++j) {
            const uint chunk = (uint)(j * 4 + w);
            const uint o = chunk * 1024u + (uint)lane * 16u;
            const uint rrow = o >> 9;
            const uint bo = o & 511u;
            int grow = row0 + (int)rrow;
            if (grow > NN - 1) grow = NN - 1;
            const char* src = (const char*)X + (size_t)grow * 512 + swzA(rrow, bo);
            __builtin_amdgcn_global_load_lds((const AS1 void*)src,
                                             (AS3 void*)(As[0] + chunk * 1024), 16, 0, 0);
        }
    }
    __syncthreads();

    const uint arow = (uint)(wm * 32 + (lane & 31));

    for (int r = 0; r < nt; ++r) {
        const int cur = r & 1;
        // ---- issue next tile's loads into the other buffer (async)
        if (r + 1 < nt) {
            const int row0n = (bid + (r + 1) * 512) * 64;
            #pragma unroll
            for (int j = 0; j < 8; ++j) {
                const uint chunk = (uint)(j * 4 + w);
                const uint o = chunk * 1024u + (uint)lane * 16u;
                const uint rrow = o >> 9;
                const uint bo = o & 511u;
                int grow = row0n + (int)rrow;
                if (grow > NN - 1) grow = NN - 1;
                const char* src = (const char*)X + (size_t)grow * 512 + swzA(rrow, bo);
                __builtin_amdgcn_global_load_lds((const AS1 void*)src,
                                                 (AS3 void*)(As[cur ^ 1] + chunk * 1024),
                                                 16, 0, 0);
            }
        }
        __builtin_amdgcn_sched_barrier(0);   // pin: issue prefetch before compute

        // ---- compute current tile (LDS + registers only)
        const int row0 = (bid + r * 512) * 64;
        const char* abase = As[cur] + arow * 512;

        f32x16 acc[4];
        #pragma unroll
        for (int n = 0; n < 4; ++n)
            acc[n] = (f32x16){0,0,0,0,0,0,0,0,0,0,0,0,0,0,0,0};

        #pragma unroll
        for (int kk = 0; kk < 8; ++kk) {
            const uint bo = (uint)(kk * 64 + (lane >> 5) * 32);
            const float4 fa = *(const float4*)(abase + swzA(arow, bo));
            const float4 fb = *(const float4*)(abase + swzA(arow, bo + 16));
            const s16x8 a = pack8(fa, fb);
            #pragma unroll
            for (int n = 0; n < 4; ++n) {
                // swapped: W as A (row=feature), X as B (col=node)
                acc[n] = __builtin_amdgcn_mfma_f32_32x32x16_bf16(Bf[kk * 4 + n], a, acc[n], 0, 0, 0);
            }
        }

        // ---- epilogue: lane owns node; 16 contiguous pi-positions per frag
        const int node = row0 + wm * 32 + (lane & 31);
        if (node < NN) {
            const int h16 = (lane >> 5) * 16;
            if (wn == 0) {
                ushort* qp = Qb + (size_t)node * HID + h16;
                #pragma unroll
                for (int n = 0; n < 4; ++n) {
                    uint4 u0, u1;
                    u0.x = cvtpk(acc[n][0], acc[n][1]);
                    u0.y = cvtpk(acc[n][2], acc[n][3]);
                    u0.z = cvtpk(acc[n][4], acc[n][5]);
                    u0.w = cvtpk(acc[n][6], acc[n][7]);
                    u1.x = cvtpk(acc[n][8], acc[n][9]);
                    u1.y = cvtpk(acc[n][10], acc[n][11]);
                    u1.z = cvtpk(acc[n][12], acc[n][13]);
                    u1.w = cvtpk(acc[n][14], acc[n][15]);
                    *(uint4*)(qp + n * 32) = u0;
                    *(uint4*)(qp + n * 32 + 8) = u1;
                }
            } else {
                unsigned char* pp = Pf + (size_t)node * HID + h16;
                #pragma unroll
                for (int n = 0; n < 4; ++n) {
                    uint uu[4];
                    #pragma unroll
                    for (int q = 0; q < 4; ++q) {
                        int v = __builtin_amdgcn_cvt_pk_fp8_f32(
                            acc[n][4 * q], acc[n][4 * q + 1], 0, false);
                        v = __builtin_amdgcn_cvt_pk_fp8_f32(
                            acc[n][4 * q + 2], acc[n][4 * q + 3], v, true);
                        uu[q] = (uint)v;
                    }
                    *(uint4*)(pp + n * 32) = *(const uint4*)uu;
                }
            }
        }
        __syncthreads();   // next tile's loads landed; everyone done with As[cur]
    }
}

// ---------------------------------------------------------------------------
// Fused aggregate + GEMM2 (all pi-ordered; elementwise ops order-agnostic).
// Block = 128 nodes, 32KB LDS. (256,3): 3 blocks/CU.
// Phase A: h1[n] = relu(Qb[n] + mean_d Pf[nbr(n,d)]) -> swizzled LDS (bf16).
// Phase B: ST = h1pi @ WF2pi (MFMA from LDS) -> STb (bf16, true order).
// ---------------------------------------------------------------------------
__global__ __launch_bounds__(256, 3)
void agg_gemm2(const int* __restrict__ nidx, const unsigned char* __restrict__ Pf,
               const ushort* __restrict__ Qb, const ushort* __restrict__ WF2,
               ushort* __restrict__ STb) {
    __shared__ char hs[128 * 256];  // 32KB: 128 rows x 128 bf16, swizzled
    const int t = threadIdx.x;
    const int node0 = blockIdx.x * 128;
    const int sl = t & 7;    // 16B fp8-slice of a row (16 elems)
    const int ng = t >> 3;   // node slot 0..31

    const float inv = 1.0f / 16.0f;
    #pragma unroll 1
    for (int it = 0; it < 4; ++it) {
        const int r = ng + it * 32;          // local row 0..127
        int node = node0 + r;
        if (node > NN - 1) node = NN - 1;
        const int2 myn = *(const int2*)(nidx + (size_t)node * DEG + sl * 2);
        const ushort* qp = Qb + (size_t)node * HID + sl * 16;
        const s16x8 q0 = *(const s16x8*)qp;
        const s16x8 q1 = *(const s16x8*)(qp + 8);

        uint4 vv[16];
        #pragma unroll
        for (int d = 0; d < 16; ++d) {
            const uint id = (uint)__shfl((d & 1) ? myn.y : myn.x, d >> 1, 8);
            vv[d] = *(const uint4*)(Pf + (size_t)id * HID + sl * 16);
        }
        __builtin_amdgcn_sched_barrier(0);   // all 16 gathers in flight first

        float s[16];
        #pragma unroll
        for (int j = 0; j < 16; ++j) s[j] = 0.f;
        #pragma unroll
        for (int d = 0; d < 16; ++d) {
            const uint wd[4] = {vv[d].x, vv[d].y, vv[d].z, vv[d].w};
            #pragma unroll
            for (int q = 0; q < 4; ++q) {
                const auto plo = __builtin_amdgcn_cvt_pk_f32_fp8(wd[q], false);
                const auto phi = __builtin_amdgcn_cvt_pk_f32_fp8(wd[q], true);
                s[q * 4 + 0] += plo[0]; s[q * 4 + 1] += plo[1];
                s[q * 4 + 2] += phi[0]; s[q * 4 + 3] += phi[1];
            }
        }

        float h[16];
        #pragma unroll
        for (int j = 0; j < 8; ++j) {
            h[j]     = fmaxf(fmaf(s[j],     inv, bf2f((ushort)q0[j])), 0.f);
            h[j + 8] = fmaxf(fmaf(s[j + 8], inv, bf2f((ushort)q1[j])), 0.f);
        }
        uint4 u0, u1;
        u0.x = cvtpk(h[0], h[1]);   u0.y = cvtpk(h[2], h[3]);
        u0.z = cvtpk(h[4], h[5]);   u0.w = cvtpk(h[6], h[7]);
        u1.x = cvtpk(h[8], h[9]);   u1.y = cvtpk(h[10], h[11]);
        u1.z = cvtpk(h[12], h[13]); u1.w = cvtpk(h[14], h[15]);
        *(uint4*)(hs + swz16(r, sl * 32)) = u0;
        *(uint4*)(hs + swz16(r, sl * 32 + 16)) = u1;
    }
    __syncthreads();

    // Phase B: 4 waves; wave w -> local rows w*32 .. w*32+31 (1 frag)
    const int lane = t & 63;
    const int w = t >> 6;
    const int rl = w * 32;

    f32x16 acc = {0,0,0,0,0,0,0,0,0,0,0,0,0,0,0,0};
    #pragma unroll
    for (int kk = 0; kk < 8; ++kk) {
        const int kb = kk * 32 + (lane >> 5) * 16;
        const s16x8 a = *(const s16x8*)(hs + swz16(rl + (lane & 31), kb));
        const s16x8 b = *(const s16x8*)(WF2 + (size_t)(kk * 64 + lane) * 8);
        acc = __builtin_amdgcn_mfma_f32_32x32x16_bf16(a, b, acc, 0, 0, 0);
    }

    const int col = lane & 31;
    const int crow4 = 4 * (lane >> 5);
    #pragma unroll
    for (int g = 0; g < 16; g += 2) {
        const uint pk = cvtpk(acc[g], acc[g + 1]);
        const int row = node0 + rl + (g & 3) + 8 * (g >> 2) + crow4;
        if (row < NN)     STb[(size_t)row * 32 + col] = (ushort)pk;
        if (row + 1 < NN) STb[(size_t)(row + 1) * 32 + col] = (ushort)(pk >> 16);
    }
}

// ---------------------------------------------------------------------------
// Final: out[b][j] = S[node_b][j] + (1/16)*sum_d T[nbr(node_b,d)][j]
// ---------------------------------------------------------------------------
__global__ __launch_bounds__(256)
void final_out(const int* __restrict__ nodes, const int* __restrict__ nidx,
               const ushort* __restrict__ STb, float* __restrict__ out) {
    const int g = blockIdx.x * 256 + threadIdx.x;
    if (g >= NB * NC / 2) return;
    const int b = g >> 3;
    const int jp = g & 7;
    const int node = nodes[b];
    const uint sv = *(const uint*)(STb + (size_t)node * 32 + jp * 2);
    const int* nb = nidx + (size_t)node * DEG;
    float a0 = 0.f, a1 = 0.f;
    #pragma unroll
    for (int d = 0; d < DEG; ++d) {
        const uint v = *(const uint*)(STb + (size_t)nb[d] * 32 + 16 + jp * 2);
        a0 += bf2f((ushort)v);
        a1 += bf2f((ushort)(v >> 16));
    }
    float2 o;
    o.x = fmaf(a0, 1.0f / 16.0f, bf2f((ushort)sv));
    o.y = fmaf(a1, 1.0f / 16.0f, bf2f((ushort)(sv >> 16)));
    *(float2*)(out + (size_t)b * 16 + jp * 2) = o;
}

extern "C" void kernel_launch(void* const* d_in, const int* in_sizes, int n_in,
                              void* d_out, int out_size, void* d_ws, size_t ws_size,
                              hipStream_t stream) {
    const int* nodes = (const int*)d_in[0];
    const int* nidx  = (const int*)d_in[1];
    const float* X   = (const float*)d_in[2];
    const float* W1  = (const float*)d_in[3];
    const float* W2  = (const float*)d_in[4];
    float* out = (float*)d_out;

    // ws: Qb bf16 25.6MB | Pf fp8 12.8MB | STb bf16 6.4MB | WFh 64KB | WF2 8KB
    ushort* Qb = (ushort*)d_ws;
    unsigned char* Pf = (unsigned char*)(Qb + (size_t)NN * HID);
    ushort* STb = (ushort*)(Pf + (size_t)NN * HID);
    ushort* WFh = STb + (size_t)NN * 32;
    ushort* WF2 = WFh + 64 * 64 * 8;

    wf_prep<<<18, 256, 0, stream>>>(W1, W2, WFh, WF2);
    gemm1<<<512, 256, 0, stream>>>(X, WFh, Qb, Pf);   // grid-strided: 512 blocks, 3-4 tiles
    agg_gemm2<<<782, 256, 0, stream>>>(nidx, Pf, Qb, WF2, STb);
    final_out<<<313, 256, 0, stream>>>(nodes, nidx, STb, out);
}